// Round 1
// baseline (267.747 us; speedup 1.0000x reference)
//
#include <hip/hip_runtime.h>
#include <hip/hip_bf16.h>

#define O_DIM 4096
#define I_DIM 4096
#define B_DIM 512

typedef short bf16x8 __attribute__((ext_vector_type(8)));
typedef float f32x4 __attribute__((ext_vector_type(4)));

__device__ __forceinline__ unsigned short f2bf(float x) {
    return __builtin_bit_cast(unsigned short, __float2bfloat16(x));
}

// ---------------------------------------------------------------------------
// Kernel 1: gumbel-argmax mask + masked weights -> bf16
// t_k = l_k - log(-log(u_k + 1e-20) + 1e-20); argmax_k (first-index ties)
// fast f32 path with __logf; f64 fallback when margin < 1e-3 to match the
// f64 numpy reference's decisions exactly.
// ---------------------------------------------------------------------------
__global__ __launch_bounds__(256) void mask_kernel(
    const float* __restrict__ wts,
    const float* __restrict__ pb, const float* __restrict__ pf,
    const float* __restrict__ pp, const float* __restrict__ noise,
    unsigned short* __restrict__ wm)
{
    const int total4 = (O_DIM * I_DIM) / 4;
    int stride = gridDim.x * blockDim.x;
    for (int q = blockIdx.x * blockDim.x + threadIdx.x; q < total4; q += stride) {
        float4 b4 = ((const float4*)pb)[q];
        float4 f4 = ((const float4*)pf)[q];
        float4 p4 = ((const float4*)pp)[q];
        float4 w4 = ((const float4*)wts)[q];
        float4 n0 = ((const float4*)noise)[(long)q*3 + 0];
        float4 n1 = ((const float4*)noise)[(long)q*3 + 1];
        float4 n2 = ((const float4*)noise)[(long)q*3 + 2];
        float lb[4] = {b4.x, b4.y, b4.z, b4.w};
        float lf[4] = {f4.x, f4.y, f4.z, f4.w};
        float lp[4] = {p4.x, p4.y, p4.z, p4.w};
        float wv[4] = {w4.x, w4.y, w4.z, w4.w};
        float uu[12] = {n0.x,n0.y,n0.z,n0.w, n1.x,n1.y,n1.z,n1.w, n2.x,n2.y,n2.z,n2.w};
        unsigned short out[4];
        #pragma unroll
        for (int j = 0; j < 4; ++j) {
            float u0 = uu[3*j+0], u1 = uu[3*j+1], u2 = uu[3*j+2];
            float t0 = lb[j] - __logf(-__logf(u0 + 1e-20f) + 1e-20f);
            float t1 = lf[j] - __logf(-__logf(u1 + 1e-20f) + 1e-20f);
            float t2 = lp[j] - __logf(-__logf(u2 + 1e-20f) + 1e-20f);
            int k = 0; float best = t0;
            if (t1 > best) { best = t1; k = 1; }
            if (t2 > best) { best = t2; k = 2; }
            float sec = (k == 0) ? fmaxf(t1, t2)
                      : (k == 1) ? fmaxf(t0, t2) : fmaxf(t0, t1);
            if (best - sec < 1e-3f) {  // near-tie: resolve in f64 (rare)
                double d0 = (double)lb[j] - log(-log((double)u0 + 1e-20) + 1e-20);
                double d1 = (double)lf[j] - log(-log((double)u1 + 1e-20) + 1e-20);
                double d2 = (double)lp[j] - log(-log((double)u2 + 1e-20) + 1e-20);
                k = 0; double db = d0;
                if (d1 > db) { db = d1; k = 1; }
                if (d2 > db) { k = 2; }
            }
            float mw = (k == 0) ? wv[j] : (k == 1) ? -wv[j] : 0.0f;
            out[j] = f2bf(mw);
        }
        ushort4 o4 = {out[0], out[1], out[2], out[3]};
        ((ushort4*)wm)[q] = o4;
    }
}

// ---------------------------------------------------------------------------
// Kernel 2: x (f32) -> bf16
// ---------------------------------------------------------------------------
__global__ __launch_bounds__(256) void cvt_kernel(
    const float* __restrict__ x, unsigned short* __restrict__ xb)
{
    const int total4 = (B_DIM * I_DIM) / 4;
    int stride = gridDim.x * blockDim.x;
    for (int q = blockIdx.x * blockDim.x + threadIdx.x; q < total4; q += stride) {
        float4 v = ((const float4*)x)[q];
        ushort4 o = {f2bf(v.x), f2bf(v.y), f2bf(v.z), f2bf(v.w)};
        ((ushort4*)xb)[q] = o;
    }
}

// ---------------------------------------------------------------------------
// Kernel 3: C[b][o] = sum_k xb[b][k] * wm[o][k] + bias[o]
// BM=64, BN=128, BK=64; 256 threads = 4 waves (2x2), per-wave 32x64 output.
// mfma_f32_16x16x32_bf16; A/B frag: row/col = lane&15, k = (lane>>4)*8 + j.
// C frag: col = lane&15, row = (lane>>4)*4 + reg  (m89-verified).
// LDS rows padded +8 bf16 (stride 144B = 9*16B: keeps b128 alignment,
// rows 0..7 hit distinct 4-bank groups -> only free 2-way aliasing).
// ---------------------------------------------------------------------------
#define BM 64
#define BN 128
#define BK 64

__global__ __launch_bounds__(256) void gemm_kernel(
    const unsigned short* __restrict__ A,   // xb [512][4096] bf16
    const unsigned short* __restrict__ Bw,  // wm [4096][4096] bf16
    const float* __restrict__ bias,
    float* __restrict__ C)
{
    __shared__ unsigned short As[BM][72];
    __shared__ unsigned short Bs[BN][72];
    const int K = I_DIM, N = O_DIM;
    int tid = threadIdx.x;
    int bm0 = (blockIdx.x & 7) * BM;
    int bn0 = (blockIdx.x >> 3) * BN;
    int wid = tid >> 6, l = tid & 63;
    int wr = wid >> 1, wc = wid & 1;      // 2x2 wave grid
    int lrow = l & 15;
    int lk = (l >> 4) * 8;

    f32x4 acc[2][4] = {};

    for (int k0 = 0; k0 < K; k0 += BK) {
        // stage A: 64x64 bf16 = 512 granules of 16B
        #pragma unroll
        for (int it = 0; it < 2; ++it) {
            int g = tid + it * 256;
            int row = g >> 3, cg = g & 7;
            uint4 v = *(const uint4*)(&A[(bm0 + row) * K + k0 + cg * 8]);
            *(uint4*)(&As[row][cg * 8]) = v;
        }
        // stage B: 128x64 bf16 = 1024 granules
        #pragma unroll
        for (int it = 0; it < 4; ++it) {
            int g = tid + it * 256;
            int row = g >> 3, cg = g & 7;
            uint4 v = *(const uint4*)(&Bw[(bn0 + row) * K + k0 + cg * 8]);
            *(uint4*)(&Bs[row][cg * 8]) = v;
        }
        __syncthreads();
        #pragma unroll
        for (int kk = 0; kk < 2; ++kk) {
            bf16x8 a[2], b[4];
            #pragma unroll
            for (int m = 0; m < 2; ++m)
                a[m] = *(const bf16x8*)(&As[wr * 32 + m * 16 + lrow][kk * 32 + lk]);
            #pragma unroll
            for (int n = 0; n < 4; ++n)
                b[n] = *(const bf16x8*)(&Bs[wc * 64 + n * 16 + lrow][kk * 32 + lk]);
            #pragma unroll
            for (int m = 0; m < 2; ++m)
                #pragma unroll
                for (int n = 0; n < 4; ++n)
                    acc[m][n] = __builtin_amdgcn_mfma_f32_16x16x32_bf16(
                        a[m], b[n], acc[m][n], 0, 0, 0);
        }
        __syncthreads();
    }

    // epilogue: C row = (l>>4)*4 + r, col = l&15
    int crow0 = bm0 + wr * 32 + (l >> 4) * 4;
    #pragma unroll
    for (int n = 0; n < 4; ++n) {
        int col = bn0 + wc * 64 + n * 16 + (l & 15);
        float bv = bias[col];
        #pragma unroll
        for (int m = 0; m < 2; ++m)
            #pragma unroll
            for (int r = 0; r < 4; ++r)
                C[(crow0 + m * 16 + r) * N + col] = acc[m][n][r] + bv;
    }
}

extern "C" void kernel_launch(void* const* d_in, const int* in_sizes, int n_in,
                              void* d_out, int out_size, void* d_ws, size_t ws_size,
                              hipStream_t stream) {
    const float* x    = (const float*)d_in[0];
    const float* wts  = (const float*)d_in[1];
    const float* bias = (const float*)d_in[2];
    const float* pb   = (const float*)d_in[3];
    const float* pf   = (const float*)d_in[4];
    const float* pp   = (const float*)d_in[5];
    const float* un   = (const float*)d_in[6];
    float* out = (float*)d_out;

    unsigned short* wm = (unsigned short*)d_ws;              // 32 MB bf16 masked W
    unsigned short* xb = wm + (size_t)O_DIM * I_DIM;         // 4 MB bf16 x

    mask_kernel<<<2048, 256, 0, stream>>>(wts, pb, pf, pp, un, wm);
    cvt_kernel<<<512, 256, 0, stream>>>(x, xb);
    gemm_kernel<<<dim3((O_DIM / BN) * (B_DIM / BM)), 256, 0, stream>>>(xb, wm, bias, out);
}

// Round 2
// 164.150 us; speedup vs baseline: 1.6311x; 1.6311x over previous
//
#include <hip/hip_runtime.h>
#include <hip/hip_bf16.h>

#define O_DIM 4096
#define I_DIM 4096
#define B_DIM 512

typedef short bf16x8 __attribute__((ext_vector_type(8)));
typedef float f32x4 __attribute__((ext_vector_type(4)));

__device__ __forceinline__ unsigned short f2bf(float x) {
    return __builtin_bit_cast(unsigned short, __float2bfloat16(x));
}

// ---------------------------------------------------------------------------
// Kernel 1: gumbel-argmax mask + masked weights -> bf16
// fast f32 path with __logf; f64 fallback when margin < 1e-3 so argmax
// decisions match the f64 numpy reference exactly.
// ---------------------------------------------------------------------------
__global__ __launch_bounds__(256) void mask_kernel(
    const float* __restrict__ wts,
    const float* __restrict__ pb, const float* __restrict__ pf,
    const float* __restrict__ pp, const float* __restrict__ noise,
    unsigned short* __restrict__ wm)
{
    const int total4 = (O_DIM * I_DIM) / 4;
    int stride = gridDim.x * blockDim.x;
    for (int q = blockIdx.x * blockDim.x + threadIdx.x; q < total4; q += stride) {
        float4 b4 = ((const float4*)pb)[q];
        float4 f4 = ((const float4*)pf)[q];
        float4 p4 = ((const float4*)pp)[q];
        float4 w4 = ((const float4*)wts)[q];
        float4 n0 = ((const float4*)noise)[(long)q*3 + 0];
        float4 n1 = ((const float4*)noise)[(long)q*3 + 1];
        float4 n2 = ((const float4*)noise)[(long)q*3 + 2];
        float lb[4] = {b4.x, b4.y, b4.z, b4.w};
        float lf[4] = {f4.x, f4.y, f4.z, f4.w};
        float lp[4] = {p4.x, p4.y, p4.z, p4.w};
        float wv[4] = {w4.x, w4.y, w4.z, w4.w};
        float uu[12] = {n0.x,n0.y,n0.z,n0.w, n1.x,n1.y,n1.z,n1.w, n2.x,n2.y,n2.z,n2.w};
        unsigned short out[4];
        #pragma unroll
        for (int j = 0; j < 4; ++j) {
            float u0 = uu[3*j+0], u1 = uu[3*j+1], u2 = uu[3*j+2];
            float t0 = lb[j] - __logf(-__logf(u0 + 1e-20f) + 1e-20f);
            float t1 = lf[j] - __logf(-__logf(u1 + 1e-20f) + 1e-20f);
            float t2 = lp[j] - __logf(-__logf(u2 + 1e-20f) + 1e-20f);
            int k = 0; float best = t0;
            if (t1 > best) { best = t1; k = 1; }
            if (t2 > best) { best = t2; k = 2; }
            float sec = (k == 0) ? fmaxf(t1, t2)
                      : (k == 1) ? fmaxf(t0, t2) : fmaxf(t0, t1);
            if (best - sec < 1e-3f) {  // near-tie: resolve in f64 (rare)
                double d0 = (double)lb[j] - log(-log((double)u0 + 1e-20) + 1e-20);
                double d1 = (double)lf[j] - log(-log((double)u1 + 1e-20) + 1e-20);
                double d2 = (double)lp[j] - log(-log((double)u2 + 1e-20) + 1e-20);
                k = 0; double db = d0;
                if (d1 > db) { db = d1; k = 1; }
                if (d2 > db) { k = 2; }
            }
            float mw = (k == 0) ? wv[j] : (k == 1) ? -wv[j] : 0.0f;
            out[j] = f2bf(mw);
        }
        ushort4 o4 = {out[0], out[1], out[2], out[3]};
        ((ushort4*)wm)[q] = o4;
    }
}

// ---------------------------------------------------------------------------
// Kernel 2: x (f32) -> bf16
// ---------------------------------------------------------------------------
__global__ __launch_bounds__(256) void cvt_kernel(
    const float* __restrict__ x, unsigned short* __restrict__ xb)
{
    const int total4 = (B_DIM * I_DIM) / 4;
    int stride = gridDim.x * blockDim.x;
    for (int q = blockIdx.x * blockDim.x + threadIdx.x; q < total4; q += stride) {
        float4 v = ((const float4*)x)[q];
        ushort4 o = {f2bf(v.x), f2bf(v.y), f2bf(v.z), f2bf(v.w)};
        ((ushort4*)xb)[q] = o;
    }
}

// ---------------------------------------------------------------------------
// Kernel 3: C[b][o] = sum_k xb[b][k] * wm[o][k] + bias[o]
// BM=BN=64, BK=64, 256 thr (4 waves, 2x2), wave tile 32x32 (2x2 frags of
// 16x16x32). Double-buffered LDS staged with global_load_lds width=16
// (linear dest). Bank-conflict fix per rule #21: XOR-swizzle chunk^=(row&7)
// applied to the GLOBAL source address AND to the ds_read address (same
// involution), LDS itself stays linear. One __syncthreads per K-step
// (T3-min 2-phase: stage next -> compute cur -> drain+barrier).
// Grid 512 = 8 bm x 64 bn; decode bn = idx&63 so the 8 blocks sharing a
// B-panel land on one XCD (panel set = 8 x 512KB = 4MB = one L2).
// ---------------------------------------------------------------------------
#define BM 64
#define BN 64
#define BK 64
#define NT (I_DIM / BK)

__global__ __launch_bounds__(256, 2) void gemm_kernel(
    const unsigned short* __restrict__ A,   // xb [512][4096] bf16
    const unsigned short* __restrict__ Bw,  // wm [4096][4096] bf16
    const float* __restrict__ bias,
    float* __restrict__ C)
{
    __shared__ unsigned short Asm[2][BM * BK];  // 16 KB
    __shared__ unsigned short Bsm[2][BN * BK];  // 16 KB
    const int K = I_DIM;

    int tid = threadIdx.x;
    int w = tid >> 6, l = tid & 63;
    int bm0 = (blockIdx.x >> 6) * BM;
    int bn0 = (blockIdx.x & 63) * BN;
    int wr = w >> 1, wc = w & 1;          // 2x2 wave grid
    int lrow = l & 15, lhi = l >> 4, swz = l & 7;

    // staging geometry: per issue j, wave w writes LDS rows j*32+w*8 .. +7,
    // lane i -> row i/8, chunk i%8 (16B chunks). Global chunk pre-swizzled.
    int srow = l >> 3;                    // 0..7
    int schunk = (l & 7) ^ srow;          // inverse-swizzled source chunk

    f32x4 acc[2][2] = {};

#define STAGE(buf, k0)                                                         \
    {                                                                          \
        _Pragma("unroll")                                                      \
        for (int j = 0; j < 2; ++j) {                                          \
            int rr = j * 32 + w * 8 + srow;                                    \
            const unsigned short* sa = &A[(size_t)(bm0 + rr) * K + (k0) + schunk * 8];  \
            const unsigned short* sb = &Bw[(size_t)(bn0 + rr) * K + (k0) + schunk * 8]; \
            __builtin_amdgcn_global_load_lds(                                  \
                (const __attribute__((address_space(1))) void*)sa,             \
                (__attribute__((address_space(3))) void*)&Asm[buf][(j * 32 + w * 8) * BK], \
                16, 0, 0);                                                     \
            __builtin_amdgcn_global_load_lds(                                  \
                (const __attribute__((address_space(1))) void*)sb,             \
                (__attribute__((address_space(3))) void*)&Bsm[buf][(j * 32 + w * 8) * BK], \
                16, 0, 0);                                                     \
        }                                                                      \
    }

    STAGE(0, 0);
    __syncthreads();

    for (int t = 0; t < NT; ++t) {
        int cur = t & 1;
        if (t + 1 < NT) STAGE(cur ^ 1, (t + 1) * BK);

        bf16x8 a[2][2], b[2][2];
        #pragma unroll
        for (int kk = 0; kk < 2; ++kk) {
            #pragma unroll
            for (int m = 0; m < 2; ++m)
                a[kk][m] = *(const bf16x8*)&Asm[cur][(wr * 32 + m * 16 + lrow) * BK +
                                                     (((kk * 4 + lhi) ^ swz) * 8)];
            #pragma unroll
            for (int n = 0; n < 2; ++n)
                b[kk][n] = *(const bf16x8*)&Bsm[cur][(wc * 32 + n * 16 + lrow) * BK +
                                                     (((kk * 4 + lhi) ^ swz) * 8)];
        }
        #pragma unroll
        for (int kk = 0; kk < 2; ++kk)
            #pragma unroll
            for (int m = 0; m < 2; ++m)
                #pragma unroll
                for (int n = 0; n < 2; ++n)
                    acc[m][n] = __builtin_amdgcn_mfma_f32_16x16x32_bf16(
                        a[kk][m], b[kk][n], acc[m][n], 0, 0, 0);

        __syncthreads();   // drains vmcnt (stage) + lgkmcnt, swaps buffers
    }
#undef STAGE

    // epilogue: C frag row=(l>>4)*4+r, col=l&15 (m89-verified)
    int crow0 = bm0 + wr * 32 + lhi * 4;
    #pragma unroll
    for (int n = 0; n < 2; ++n) {
        int col = bn0 + wc * 32 + n * 16 + lrow;
        float bv = bias[col];
        #pragma unroll
        for (int m = 0; m < 2; ++m)
            #pragma unroll
            for (int r = 0; r < 4; ++r)
                C[(size_t)(crow0 + m * 16 + r) * O_DIM + col] = acc[m][n][r] + bv;
    }
}

extern "C" void kernel_launch(void* const* d_in, const int* in_sizes, int n_in,
                              void* d_out, int out_size, void* d_ws, size_t ws_size,
                              hipStream_t stream) {
    const float* x    = (const float*)d_in[0];
    const float* wts  = (const float*)d_in[1];
    const float* bias = (const float*)d_in[2];
    const float* pb   = (const float*)d_in[3];
    const float* pf   = (const float*)d_in[4];
    const float* pp   = (const float*)d_in[5];
    const float* un   = (const float*)d_in[6];
    float* out = (float*)d_out;

    unsigned short* wm = (unsigned short*)d_ws;              // 32 MB bf16 masked W
    unsigned short* xb = wm + (size_t)O_DIM * I_DIM;         // 4 MB bf16 x

    mask_kernel<<<2048, 256, 0, stream>>>(wts, pb, pf, pp, un, wm);
    cvt_kernel<<<512, 256, 0, stream>>>(x, xb);
    gemm_kernel<<<dim3((O_DIM / BN) * (B_DIM / BM)), 256, 0, stream>>>(xb, wm, bias, out);
}